// Round 2
// baseline (153.575 us; speedup 1.0000x reference)
//
#include <hip/hip_runtime.h>
#include <hip/hip_bf16.h>

#define LOG_2PI 1.8378770664093453f

#define NBLOCKS 2000     // 512,000 threads -> exactly 8 float4 per thread at n=16,384,000
#define NTHREADS 256

__device__ __forceinline__ float nll_elem4(const float4 m, const float4 v, const float4 t) {
    float d0 = t.x - m.x;
    float d1 = t.y - m.y;
    float d2 = t.z - m.z;
    float d3 = t.w - m.w;
    float s;
    s  = d0 * d0 * __builtin_amdgcn_rcpf(v.x) + __logf(v.x);
    s += d1 * d1 * __builtin_amdgcn_rcpf(v.y) + __logf(v.y);
    s += d2 * d2 * __builtin_amdgcn_rcpf(v.z) + __logf(v.z);
    s += d3 * d3 * __builtin_amdgcn_rcpf(v.w) + __logf(v.w);
    return s;
}

// Single fused kernel: elementwise NLL + per-block reduce + last-block final
// reduce (deterministic: fixed-order sums only; the atomic is on a counter,
// not on float data). Agent-scope atomics handle cross-XCD L2 non-coherence.
__global__ void __launch_bounds__(NTHREADS)
nll_fused_kernel(const float* __restrict__ mean_,
                 const float* __restrict__ var_,
                 const float* __restrict__ tgt_,
                 float* __restrict__ partial,
                 unsigned int* __restrict__ counter,
                 float* __restrict__ out,
                 int n, float inv_n) {
    const int nvec = n >> 2;
    const int tid = blockIdx.x * blockDim.x + threadIdx.x;
    const int stride = gridDim.x * blockDim.x;

    const float4* __restrict__ m4 = reinterpret_cast<const float4*>(mean_);
    const float4* __restrict__ v4 = reinterpret_cast<const float4*>(var_);
    const float4* __restrict__ t4 = reinterpret_cast<const float4*>(tgt_);

    float s0 = 0.0f, s1 = 0.0f;

    if (nvec == stride * 8 && (n & 3) == 0) {
        // Exact bench shape: 8 float4 per thread, fully unrolled, 2 accumulators.
        #pragma unroll
        for (int k = 0; k < 8; k += 2) {
            const int i = tid + k * stride;
            const int j = i + stride;
            float4 ma = m4[i], va = v4[i], ta = t4[i];
            float4 mb = m4[j], vb = v4[j], tb = t4[j];
            s0 += nll_elem4(ma, va, ta);
            s1 += nll_elem4(mb, vb, tb);
        }
    } else {
        // Generic fallback (any n).
        int i = tid;
        for (; i + stride < nvec; i += 2 * stride) {
            const int j = i + stride;
            float4 ma = m4[i], va = v4[i], ta = t4[i];
            float4 mb = m4[j], vb = v4[j], tb = t4[j];
            s0 += nll_elem4(ma, va, ta);
            s1 += nll_elem4(mb, vb, tb);
        }
        if (i < nvec) s0 += nll_elem4(m4[i], v4[i], t4[i]);
        if (tid == 0) {
            for (int k = nvec << 2; k < n; ++k) {
                float d = tgt_[k] - mean_[k];
                s0 += d * d * __builtin_amdgcn_rcpf(var_[k]) + __logf(var_[k]);
            }
        }
    }

    float s = s0 + s1;
    #pragma unroll
    for (int off = 32; off > 0; off >>= 1)
        s += __shfl_down(s, off, 64);

    __shared__ float smem[NTHREADS / 64];
    __shared__ bool amLast;
    if ((threadIdx.x & 63) == 0) smem[threadIdx.x >> 6] = s;
    __syncthreads();

    if (threadIdx.x == 0) {
        float b = 0.0f;
        #pragma unroll
        for (int w = 0; w < NTHREADS / 64; ++w) b += smem[w];
        __hip_atomic_store(&partial[blockIdx.x], b, __ATOMIC_RELEASE,
                           __HIP_MEMORY_SCOPE_AGENT);
        unsigned int prev = __hip_atomic_fetch_add(counter, 1u, __ATOMIC_ACQ_REL,
                                                   __HIP_MEMORY_SCOPE_AGENT);
        amLast = (prev == (unsigned int)(gridDim.x - 1));
    }
    __syncthreads();

    if (amLast) {
        // Fixed-order reduction of all block partials -> deterministic result.
        float t = 0.0f;
        for (int j = threadIdx.x; j < (int)gridDim.x; j += (int)blockDim.x)
            t += __hip_atomic_load(&partial[j], __ATOMIC_RELAXED,
                                   __HIP_MEMORY_SCOPE_AGENT);
        #pragma unroll
        for (int off = 32; off > 0; off >>= 1)
            t += __shfl_down(t, off, 64);
        __shared__ float smem2[NTHREADS / 64];
        if ((threadIdx.x & 63) == 0) smem2[threadIdx.x >> 6] = t;
        __syncthreads();
        if (threadIdx.x == 0) {
            float b = 0.0f;
            #pragma unroll
            for (int w = 0; w < NTHREADS / 64; ++w) b += smem2[w];
            out[0] = b * inv_n + LOG_2PI;
        }
    }
}

extern "C" void kernel_launch(void* const* d_in, const int* in_sizes, int n_in,
                              void* d_out, int out_size, void* d_ws, size_t ws_size,
                              hipStream_t stream) {
    const float* mean_ = (const float*)d_in[0];
    const float* var_  = (const float*)d_in[1];
    const float* tgt_  = (const float*)d_in[2];
    float* out = (float*)d_out;

    float* partial = (float*)d_ws;                                   // NBLOCKS floats
    unsigned int* counter =
        (unsigned int*)((char*)d_ws + NBLOCKS * sizeof(float));      // 1 uint

    const int n = in_sizes[0];

    hipMemsetAsync(counter, 0, sizeof(unsigned int), stream);
    nll_fused_kernel<<<NBLOCKS, NTHREADS, 0, stream>>>(
        mean_, var_, tgt_, partial, counter, out, n, 1.0f / (float)n);
}

// Round 3
// 38.423 us; speedup vs baseline: 3.9970x; 3.9970x over previous
//
#include <hip/hip_runtime.h>
#include <hip/hip_bf16.h>

#define LOG_2PI 1.8378770664093453f

#define NBLOCKS 2000     // 512,000 threads -> exactly 8 float4 per thread at n=16,384,000
#define NTHREADS 256

__device__ __forceinline__ float nll_elem4(const float4 m, const float4 v, const float4 t) {
    float d0 = t.x - m.x;
    float d1 = t.y - m.y;
    float d2 = t.z - m.z;
    float d3 = t.w - m.w;
    float s;
    s  = d0 * d0 * __builtin_amdgcn_rcpf(v.x) + __logf(v.x);
    s += d1 * d1 * __builtin_amdgcn_rcpf(v.y) + __logf(v.y);
    s += d2 * d2 * __builtin_amdgcn_rcpf(v.z) + __logf(v.z);
    s += d3 * d3 * __builtin_amdgcn_rcpf(v.w) + __logf(v.w);
    return s;
}

// Kernel 1: fused elementwise + per-block reduction. Plain stores of partials
// (no ordered atomics — agent-scope release/acquire costs a full L2
// writeback/invalidate per block on multi-XCD gfx950: R2's 4x regression).
__global__ void __launch_bounds__(NTHREADS)
nll_partial_kernel(const float* __restrict__ mean_,
                   const float* __restrict__ var_,
                   const float* __restrict__ tgt_,
                   float* __restrict__ partial,
                   int n) {
    const int nvec = n >> 2;
    const int tid = blockIdx.x * blockDim.x + threadIdx.x;
    const int stride = gridDim.x * blockDim.x;

    const float4* __restrict__ m4 = reinterpret_cast<const float4*>(mean_);
    const float4* __restrict__ v4 = reinterpret_cast<const float4*>(var_);
    const float4* __restrict__ t4 = reinterpret_cast<const float4*>(tgt_);

    float s0 = 0.0f, s1 = 0.0f;

    if (nvec == stride * 8 && (n & 3) == 0) {
        // Exact bench shape: 8 float4 per thread, fully unrolled, 2 accumulators.
        #pragma unroll
        for (int k = 0; k < 8; k += 2) {
            const int i = tid + k * stride;
            const int j = i + stride;
            float4 ma = m4[i], va = v4[i], ta = t4[i];
            float4 mb = m4[j], vb = v4[j], tb = t4[j];
            s0 += nll_elem4(ma, va, ta);
            s1 += nll_elem4(mb, vb, tb);
        }
    } else {
        // Generic fallback (any n).
        int i = tid;
        for (; i + stride < nvec; i += 2 * stride) {
            const int j = i + stride;
            float4 ma = m4[i], va = v4[i], ta = t4[i];
            float4 mb = m4[j], vb = v4[j], tb = t4[j];
            s0 += nll_elem4(ma, va, ta);
            s1 += nll_elem4(mb, vb, tb);
        }
        if (i < nvec) s0 += nll_elem4(m4[i], v4[i], t4[i]);
        if (tid == 0) {
            for (int k = nvec << 2; k < n; ++k) {
                float d = tgt_[k] - mean_[k];
                s0 += d * d * __builtin_amdgcn_rcpf(var_[k]) + __logf(var_[k]);
            }
        }
    }

    float s = s0 + s1;
    #pragma unroll
    for (int off = 32; off > 0; off >>= 1)
        s += __shfl_down(s, off, 64);

    __shared__ float smem[NTHREADS / 64];
    if ((threadIdx.x & 63) == 0) smem[threadIdx.x >> 6] = s;
    __syncthreads();
    if (threadIdx.x == 0) {
        float b = 0.0f;
        #pragma unroll
        for (int w = 0; w < NTHREADS / 64; ++w) b += smem[w];
        partial[blockIdx.x] = b;
    }
}

// Kernel 2: deterministic final reduce of NBLOCKS partials -> scalar.
// out = total_sum / N + log(2*pi)
__global__ void __launch_bounds__(NTHREADS)
nll_final_kernel(const float* __restrict__ partial,
                 float* __restrict__ out,
                 int nb, float inv_n) {
    float s = 0.0f;
    for (int i = threadIdx.x; i < nb; i += blockDim.x)
        s += partial[i];

    #pragma unroll
    for (int off = 32; off > 0; off >>= 1)
        s += __shfl_down(s, off, 64);

    __shared__ float smem[NTHREADS / 64];
    if ((threadIdx.x & 63) == 0) smem[threadIdx.x >> 6] = s;
    __syncthreads();
    if (threadIdx.x == 0) {
        float b = 0.0f;
        #pragma unroll
        for (int w = 0; w < NTHREADS / 64; ++w) b += smem[w];
        out[0] = b * inv_n + LOG_2PI;
    }
}

extern "C" void kernel_launch(void* const* d_in, const int* in_sizes, int n_in,
                              void* d_out, int out_size, void* d_ws, size_t ws_size,
                              hipStream_t stream) {
    const float* mean_ = (const float*)d_in[0];
    const float* var_  = (const float*)d_in[1];
    const float* tgt_  = (const float*)d_in[2];
    float* out = (float*)d_out;
    float* partial = (float*)d_ws;   // NBLOCKS floats of scratch

    const int n = in_sizes[0];

    nll_partial_kernel<<<NBLOCKS, NTHREADS, 0, stream>>>(mean_, var_, tgt_, partial, n);
    nll_final_kernel<<<1, NTHREADS, 0, stream>>>(partial, out, NBLOCKS, 1.0f / (float)n);
}